// Round 10
// baseline (62.032 us; speedup 1.0000x reference)
//
#include <hip/hip_runtime.h>

#define N 8192
#define LOG2E 1.4426950408889634f
#define LN2   0.6931471805599453f
#define NMOM  15   // Taylor terms n = 0..14

using f4 = __attribute__((ext_vector_type(4))) float;

#if __has_builtin(__builtin_amdgcn_exp2f)
#define EXP2(x) __builtin_amdgcn_exp2f(x)
#else
#define EXP2(x) exp2f(x)
#endif

// 128 blocks x 256 threads. Projects q,k,v -> aq,kp and emits per-block
// PARTIAL moments pm[j] = sum k^j, pt[j] = sum v*k^j over its 64 elements.
__global__ __launch_bounds__(256) void proj_kernel(
    const float* __restrict__ q, const float* __restrict__ k, const float* __restrict__ v,
    const float* __restrict__ Wq, const float* __restrict__ bq,
    const float* __restrict__ Wk, const float* __restrict__ bk,
    const float* __restrict__ Wv, const float* __restrict__ bv,
    float* __restrict__ aq, float* __restrict__ kp, float* __restrict__ pmom)
{
    const int tn = threadIdx.x & 63;
    const int tb = threadIdx.x >> 6;        // 0..3, splits the B=64 reduction
    const int n  = blockIdx.x * 64 + tn;
    float sq = 0.f, sk = 0.f, sv = 0.f;
#pragma unroll
    for (int bi = 0; bi < 16; ++bi) {
        const int b = tb * 16 + bi;
        sq = fmaf(q[b * N + n], Wq[b], sq);
        sk = fmaf(k[b * N + n], Wk[b], sk);
        sv = fmaf(v[b * N + n], Wv[b], sv);
    }
    __shared__ float red[3][4][64];
    red[0][tb][tn] = sq; red[1][tb][tn] = sk; red[2][tb][tn] = sv;
    __syncthreads();
    if (tb == 0) {
        const float fq = red[0][0][tn] + red[0][1][tn] + red[0][2][tn] + red[0][3][tn];
        const float fk = red[1][0][tn] + red[1][1][tn] + red[1][2][tn] + red[1][3][tn];
        const float fv = red[2][0][tn] + red[2][1][tn] + red[2][2][tn] + red[2][3][tn];
        aq[n] = (fq + bq[0]) * 0.125f * LOG2E;   // fold 1/sqrt(dk) and log2e
        const float kq = fk + bk[0];
        const float vq = fv + bv[0];
        kp[n] = kq;

        float pm[NMOM], pt[NMOM];
        float p = 1.f;
#pragma unroll
        for (int j = 0; j < NMOM; ++j) { pm[j] = p; pt[j] = vq * p; p *= kq; }
#pragma unroll
        for (int off = 32; off; off >>= 1) {
#pragma unroll
            for (int j = 0; j < NMOM; ++j) {
                pm[j] += __shfl_xor(pm[j], off);
                pt[j] += __shfl_xor(pt[j], off);
            }
        }
        if (tn == 0) {
            float* pb = pmom + blockIdx.x * 32;
#pragma unroll
            for (int j = 0; j < NMOM; ++j) { pb[j] = pm[j]; pb[16 + j] = pt[j]; }
            pb[15] = 0.f; pb[31] = 0.f;      // keep unused slots clean
        }
    }
}

// 2048 blocks x 256 threads (4 waves), 1 row per wave, 8 blocks/CU.
// Prologue: reduce 128 partial-moment vectors -> global moments -> Horner
// row constants for this block's 4 rows (+ out[r]). Stream:
// attn[r][j] = 2^(a_r*k_j + c_r), NONTEMPORAL stores (write-once data,
// never re-read -> bypass L2 dirty-line bookkeeping).
__global__ __launch_bounds__(256, 8) void attn_kernel(
    const float* __restrict__ aq, const float* __restrict__ kp,
    const float* __restrict__ pmom,
    float* __restrict__ out, float* __restrict__ attn)
{
    __shared__ float psum[32][8];
    __shared__ float M[32];
    __shared__ float rowA[4], rowC[4];
    const int tid = threadIdx.x, lane = tid & 63, wave = tid >> 6;

    {   // partial-moment reduction: thread -> (slot j, chunk c)
        const int j = tid >> 3, c = tid & 7;
        float s = 0.f;
#pragma unroll
        for (int i = 0; i < 16; ++i) s += pmom[(c * 16 + i) * 32 + j];
        psum[j][c] = s;
    }
    __syncthreads();
    if (tid < 32) {
        static const float invf16[16] = {
            1.0f, 1.0f, 0.5f, 1.6666666666666666e-01f, 4.1666666666666664e-02f,
            8.3333333333333332e-03f, 1.3888888888888889e-03f, 1.9841269841269841e-04f,
            2.4801587301587302e-05f, 2.7557319223985893e-06f, 2.7557319223985888e-07f,
            2.5052108385441720e-08f, 2.0876756987868100e-09f, 1.6059043836821613e-10f,
            1.1470745597729725e-11f, 0.0f };
        float s = 0.f;
#pragma unroll
        for (int c = 0; c < 8; ++c) s += psum[tid][c];
        M[tid] = s * invf16[tid & 15];
    }
    __syncthreads();
    if (tid < 4) {
        const int r = blockIdx.x * 4 + tid;
        const float a2 = aq[r];              // log2-domain coefficient
        const float b  = a2 * LN2;           // natural-domain coefficient
        float s = M[NMOM - 1], t = M[16 + NMOM - 1];
#pragma unroll
        for (int nn = NMOM - 2; nn >= 0; --nn) {
            s = fmaf(s, b, M[nn]);
            t = fmaf(t, b, M[16 + nn]);
        }
        out[r] = t / s;
        rowA[tid] = a2;
        rowC[tid] = -__log2f(s);
    }
    __syncthreads();

    // pure store stream: one row per wave, nontemporal
    const int r = blockIdx.x * 4 + wave;
    const float a = rowA[wave];
    const float c = rowC[wave];
    const f4* __restrict__ kp4 = reinterpret_cast<const f4*>(kp);
    f4* __restrict__ arow = reinterpret_cast<f4*>(attn + (size_t)r * N);
#pragma unroll 8
    for (int it = 0; it < 32; ++it) {
        const f4 kk = kp4[lane + it * 64];
        f4 w;
        w[0] = EXP2(fmaf(a, kk[0], c));
        w[1] = EXP2(fmaf(a, kk[1], c));
        w[2] = EXP2(fmaf(a, kk[2], c));
        w[3] = EXP2(fmaf(a, kk[3], c));
        __builtin_nontemporal_store(w, &arow[lane + it * 64]);
    }
}

extern "C" void kernel_launch(void* const* d_in, const int* in_sizes, int n_in,
                              void* d_out, int out_size, void* d_ws, size_t ws_size,
                              hipStream_t stream)
{
    const float* q  = (const float*)d_in[0];
    const float* k  = (const float*)d_in[1];
    const float* v  = (const float*)d_in[2];
    const float* Wq = (const float*)d_in[3];
    const float* bq = (const float*)d_in[4];
    const float* Wk = (const float*)d_in[5];
    const float* bk = (const float*)d_in[6];
    const float* Wv = (const float*)d_in[7];
    const float* bv = (const float*)d_in[8];

    float* out  = (float*)d_out;       // [N]  (first output)
    float* attn = out + N;             // [N,N] (second output)

    float* kp   = (float*)d_ws;        // projected k
    float* aq   = kp + N;              // qp * (1/8) * log2e
    float* pmom = aq + N;              // [128][32] partial moments

    proj_kernel<<<128, 256, 0, stream>>>(q, k, v, Wq, bq, Wk, bk, Wv, bv, aq, kp, pmom);
    attn_kernel<<<2048, 256, 0, stream>>>(aq, kp, pmom, out, attn);
}

// Round 11
// 54.589 us; speedup vs baseline: 1.1363x; 1.1363x over previous
//
#include <hip/hip_runtime.h>

#define N 8192
#define LOG2E 1.4426950408889634f
#define LN2   0.6931471805599453f
#define NMOM  15   // Taylor terms n = 0..14
#define PBLK  256  // proj blocks / pmom rows

using f4 = __attribute__((ext_vector_type(4))) float;

#if __has_builtin(__builtin_amdgcn_exp2f)
#define EXP2(x) __builtin_amdgcn_exp2f(x)
#else
#define EXP2(x) exp2f(x)
#endif

// 256 blocks x 256 threads: all CUs busy. Each block: 32 n-values,
// 8-way b-split (8-deep serial fma chains). Emits per-block partial
// moments pm[j] = sum k^j, pt[j] = sum v*k^j over its 32 elements.
__global__ __launch_bounds__(256) void proj_kernel(
    const float* __restrict__ q, const float* __restrict__ k, const float* __restrict__ v,
    const float* __restrict__ Wq, const float* __restrict__ bq,
    const float* __restrict__ Wk, const float* __restrict__ bk,
    const float* __restrict__ Wv, const float* __restrict__ bv,
    float* __restrict__ aq, float* __restrict__ kp, float* __restrict__ pmom)
{
    const int tid = threadIdx.x;
    const int tn  = tid & 31;               // n within block
    const int tb  = tid >> 5;               // 0..7, splits the B=64 reduction
    const int n   = blockIdx.x * 32 + tn;
    float sq = 0.f, sk = 0.f, sv = 0.f;
#pragma unroll
    for (int bi = 0; bi < 8; ++bi) {
        const int b = tb * 8 + bi;
        sq = fmaf(q[b * N + n], Wq[b], sq);
        sk = fmaf(k[b * N + n], Wk[b], sk);
        sv = fmaf(v[b * N + n], Wv[b], sv);
    }
    __shared__ float red[3][8][32];
    __shared__ float kvs[32], vvs[32];
    red[0][tb][tn] = sq; red[1][tb][tn] = sk; red[2][tb][tn] = sv;
    __syncthreads();
    if (tid < 32) {
        float fq = 0.f, fk = 0.f, fv = 0.f;
#pragma unroll
        for (int t = 0; t < 8; ++t) {
            fq += red[0][t][tid]; fk += red[1][t][tid]; fv += red[2][t][tid];
        }
        const int nn = blockIdx.x * 32 + tid;
        aq[nn] = (fq + bq[0]) * 0.125f * LOG2E;  // fold 1/sqrt(dk) and log2e
        const float kq = fk + bk[0];
        const float vq = fv + bv[0];
        kp[nn] = kq;
        kvs[tid] = kq; vvs[tid] = vq;
    }
    __syncthreads();
    if (tid < 64) {                          // wave 0: partial moments
        const bool val = tid < 32;
        const float kq = val ? kvs[tid & 31] : 0.f;
        const float vq = val ? vvs[tid & 31] : 0.f;
        float pm[NMOM], pt[NMOM];
        float p = val ? 1.f : 0.f;
#pragma unroll
        for (int j = 0; j < NMOM; ++j) { pm[j] = p; pt[j] = vq * p; p *= kq; }
#pragma unroll
        for (int off = 32; off; off >>= 1) {
#pragma unroll
            for (int j = 0; j < NMOM; ++j) {
                pm[j] += __shfl_xor(pm[j], off);
                pt[j] += __shfl_xor(pt[j], off);
            }
        }
        if (tid == 0) {
            float* pb = pmom + blockIdx.x * 32;
#pragma unroll
            for (int j = 0; j < NMOM; ++j) { pb[j] = pm[j]; pb[16 + j] = pt[j]; }
            pb[15] = 0.f; pb[31] = 0.f;      // keep unused slots clean
        }
    }
}

// 1024 blocks x 256 threads, 4 blocks/CU (32 KB LDS). Prologue (overlapped
// with kl staging): reduce 256 partial-moment vectors -> global moments ->
// Horner row sums for this block's 8 rows; out[r] = t/s, c_r = -log2(s_r).
// Main loop: pure store stream, attn[r][j] = 2^(a_r*k_j + c_r),
// plain f4 stores (NT measured -7us worse in R10).
__global__ __launch_bounds__(256, 4) void attn_kernel(
    const float* __restrict__ aq, const float* __restrict__ kp,
    const float* __restrict__ pmom,
    float* __restrict__ out, float* __restrict__ attn)
{
    __shared__ float kl[N];                  // 32 KB
    __shared__ float psum[32][8];
    __shared__ float M[32];
    __shared__ float rowA[8], rowC[8];
    const int tid = threadIdx.x, lane = tid & 63, wave = tid >> 6;

    // issue kl staging loads first so they are in flight under the prologue
    f4 stg[8];
#pragma unroll
    for (int it = 0; it < 8; ++it)
        stg[it] = reinterpret_cast<const f4*>(kp)[tid + it * 256];

    {   // partial-moment reduction: thread -> (slot j, chunk c), 256 rows
        const int j = tid >> 3, c = tid & 7;
        float s = 0.f;
#pragma unroll
        for (int i = 0; i < 32; ++i) s += pmom[(c * 32 + i) * 32 + j];
        psum[j][c] = s;
    }
#pragma unroll
    for (int it = 0; it < 8; ++it)
        reinterpret_cast<f4*>(kl)[tid + it * 256] = stg[it];
    __syncthreads();
    if (tid < 32) {
        static const float invf16[16] = {
            1.0f, 1.0f, 0.5f, 1.6666666666666666e-01f, 4.1666666666666664e-02f,
            8.3333333333333332e-03f, 1.3888888888888889e-03f, 1.9841269841269841e-04f,
            2.4801587301587302e-05f, 2.7557319223985893e-06f, 2.7557319223985888e-07f,
            2.5052108385441720e-08f, 2.0876756987868100e-09f, 1.6059043836821613e-10f,
            1.1470745597729725e-11f, 0.0f };
        float s = 0.f;
#pragma unroll
        for (int c = 0; c < 8; ++c) s += psum[tid][c];
        M[tid] = s * invf16[tid & 15];
    }
    __syncthreads();
    if (tid < 8) {
        const int r = blockIdx.x * 8 + tid;
        const float a2 = aq[r];              // log2-domain coefficient
        const float b  = a2 * LN2;           // natural-domain coefficient
        float s = M[NMOM - 1], t = M[16 + NMOM - 1];
#pragma unroll
        for (int nn = NMOM - 2; nn >= 0; --nn) {
            s = fmaf(s, b, M[nn]);
            t = fmaf(t, b, M[16 + nn]);
        }
        out[r] = t / s;
        rowA[tid] = a2;
        rowC[tid] = -__log2f(s);
    }
    __syncthreads();

    // pure store stream: 2 rows per wave
#pragma unroll 1
    for (int rr = 0; rr < 2; ++rr) {
        const int ri = wave * 2 + rr;
        const int r  = blockIdx.x * 8 + ri;
        const float a = rowA[ri];
        const float c = rowC[ri];
        f4* __restrict__ arow = reinterpret_cast<f4*>(attn + (size_t)r * N);
#pragma unroll 8
        for (int it = 0; it < 32; ++it) {
            const f4 kk = reinterpret_cast<const f4*>(kl)[lane + it * 64];
            f4 w;
            w[0] = EXP2(fmaf(a, kk[0], c));
            w[1] = EXP2(fmaf(a, kk[1], c));
            w[2] = EXP2(fmaf(a, kk[2], c));
            w[3] = EXP2(fmaf(a, kk[3], c));
            arow[lane + it * 64] = w;
        }
    }
}

extern "C" void kernel_launch(void* const* d_in, const int* in_sizes, int n_in,
                              void* d_out, int out_size, void* d_ws, size_t ws_size,
                              hipStream_t stream)
{
    const float* q  = (const float*)d_in[0];
    const float* k  = (const float*)d_in[1];
    const float* v  = (const float*)d_in[2];
    const float* Wq = (const float*)d_in[3];
    const float* bq = (const float*)d_in[4];
    const float* Wk = (const float*)d_in[5];
    const float* bk = (const float*)d_in[6];
    const float* Wv = (const float*)d_in[7];
    const float* bv = (const float*)d_in[8];

    float* out  = (float*)d_out;       // [N]  (first output)
    float* attn = out + N;             // [N,N] (second output)

    float* kp   = (float*)d_ws;        // projected k
    float* aq   = kp + N;              // qp * (1/8) * log2e
    float* pmom = aq + N;              // [256][32] partial moments

    proj_kernel<<<PBLK, 256, 0, stream>>>(q, k, v, Wq, bq, Wk, bk, Wv, bv, aq, kp, pmom);
    attn_kernel<<<1024, 256, 0, stream>>>(aq, kp, pmom, out, attn);
}